// Round 16
// baseline (148.457 us; speedup 1.0000x reference)
//
#include <hip/hip_runtime.h>
#include <hip/hip_bf16.h>

typedef __attribute__((ext_vector_type(8))) unsigned short us8;
typedef __attribute__((ext_vector_type(8))) __bf16 bf16x8;
typedef __attribute__((ext_vector_type(4))) float f32x4;

__device__ __forceinline__ unsigned short f2bf(float f) {
  unsigned int u = __float_as_uint(f);
  u += 0x7FFFu + ((u >> 16) & 1u);   // round-to-nearest-even
  return (unsigned short)(u >> 16);
}
__device__ __forceinline__ float bf2f(unsigned short u) {
  return __uint_as_float(((unsigned int)u) << 16);
}

// direct global->LDS DMA, 16B per lane (dest = wave-uniform base + lane*16)
__device__ __forceinline__ void gld16(const unsigned short* g, unsigned short* l) {
  __builtin_amdgcn_global_load_lds(reinterpret_cast<const unsigned int*>(g),
                                   reinterpret_cast<unsigned int*>(l), 16, 0, 0);
}

// ---------------------------------------------------------------------------
// ws layout (bytes)
//   Apad : [2][132][132][256] bf16 = 17,842,176
//   BT   : [256][6400] bf16 (k=(dh*5+dw)*256+c)
//   Pp   : 2 x [32768][256] bf16 partials = 33,554,432
// total = 54,673,408
// ---------------------------------------------------------------------------
#define BT_OFF     17842176
#define PP_OFF     21118976

// --- K1: fused conv1 (blocks 0..4095) + weight prep (4096..4351) +
//         halo zero (4352..4611) --------------------------------------------
__global__ __launch_bounds__(256) void pre_k(const float* __restrict__ x,
                                             const float* __restrict__ W1,
                                             const float* __restrict__ b1,
                                             const float* __restrict__ Wp,
                                             unsigned short* __restrict__ BT,
                                             unsigned short* __restrict__ Apad) {
  __shared__ float w[6400];
  const int bid = blockIdx.x, t = threadIdx.x;
  if (bid < 4096) {
    int pxt = bid >> 3;
    int cq  = bid & 7;
    int px  = (pxt << 6) + (t & 63);
    int cg  = __builtin_amdgcn_readfirstlane(t >> 6);
    int co0 = (cq << 5) + (cg << 3);
    int b = px >> 14, hw = px & 16383;
    int h = hw >> 7, wcol = hw & 127;

    float patch[25];
#pragma unroll
    for (int dh = 0; dh < 5; ++dh)
#pragma unroll
      for (int dw = 0; dw < 5; ++dw) {
        int hh = h + dh - 2, ww = wcol + dw - 2;
        bool ok = (hh >= 0) & (hh < 128) & (ww >= 0) & (ww < 128);
        patch[dh * 5 + dw] = ok ? x[(b << 14) + hh * 128 + ww] : 0.f;
      }
    us8 o;
#pragma unroll
    for (int c = 0; c < 8; ++c) {
      float acc = b1[co0 + c];
#pragma unroll
      for (int i = 0; i < 25; ++i) acc += patch[i] * W1[(co0 + c) * 25 + i];
      o[c] = f2bf(fmaxf(acc, 0.f));
    }
    *(us8*)(Apad + (size_t)((b * 132 + h + 2) * 132 + (wcol + 2)) * 256 + co0) = o;
  } else if (bid < 4352) {
    const int n = bid - 4096;
    const float* src = Wp + n * 6400;
    for (int i = t; i < 6400; i += 256) w[i] = src[i];
    __syncthreads();
    for (int k = t; k < 6400; k += 256) {
      int dhw = k >> 8, c = k & 255;
      BT[n * 6400 + k] = f2bf(w[c * 25 + dhw]);
    }
  } else {
    int idx = (bid - 4352) * 256 + t;
    int chunk = idx & 31;
    int pix = idx >> 5;
    int img = pix >= 1040;
    int p = pix - img * 1040;
    int h, w2;
    if (p < 528) {
      int rs = p / 132;
      h = (rs < 2) ? rs : rs + 128;
      w2 = p - rs * 132;
    } else {
      int q = p - 528;
      h = 2 + (q >> 2);
      int cs = q & 3;
      w2 = (cs < 2) ? cs : cs + 128;
    }
    us8 z = {0, 0, 0, 0, 0, 0, 0, 0};
    *(us8*)(Apad + (size_t)(img * 17424 + h * 132 + w2) * 256 + chunk * 8) = z;
  }
}

// --- K2: implicit-GEMM conv (r8 sync structure + interleaved body) ---------
// 256x256 tile, 8 waves, split-K=2, 4-slot BK=32 ring (A+B in LDS, 128 KB),
// reg-double-buffered frags, ONE barrier + ONE counted VMC(4) per k-unit.
// NEW vs r8: next-unit ds_reads are source-interleaved into the MFMA cluster
// (1-2 reads after each 4-MFMA quad) instead of bursting 12 reads at the
// body boundary -> LDS port works under the MFMA window, shorter lgkm chain
// at the barrier. Sync/slots/vmcnt/numeric order identical to r8.
#define STAGE(slot, ku) do { int dhw_=(ku)>>3, dh_=dhw_/5, dw_=dhw_-dh_*5;     \
    int ao_=((dh_*132+dw_)<<8)+(((ku)&7)<<5);                                  \
    int kp_=(ku)<<5;                                                           \
    gld16(Aap+abase0+ao_, &As[slot][sA]);                                      \
    gld16(Aap+abase1+ao_, &As[slot][sA+4096]);                                 \
    gld16(BT+bbase0+kp_, &Bs[slot][sA]);                                       \
    gld16(BT+bbase1+kp_, &Bs[slot][sA+4096]); } while(0)
#define READ_SET(AST, BST, slot) do {                                          \
  _Pragma("unroll") for (int s_ = 0; s_ < 8; ++s_)                             \
    AST[s_] = *(const bf16x8*)(&As[slot][areadbase + s_*512]);                 \
  _Pragma("unroll") for (int j_ = 0; j_ < 4; ++j_)                             \
    BST[j_] = *(const bf16x8*)(&Bs[slot][breadbase + j_*512]); } while(0)
#define MFMA_SET(AST, BST) do {                                                \
  _Pragma("unroll") for (int s_ = 0; s_ < 8; ++s_)                             \
  _Pragma("unroll") for (int j_ = 0; j_ < 4; ++j_)                             \
    acc[s_][j_] = __builtin_amdgcn_mfma_f32_16x16x32_bf16(                     \
        AST[s_], BST[j_], acc[s_][j_], 0, 0, 0); } while(0)
// interleaved body: MFMA(cur) with next-unit reads sprinkled per quad
#define BODY_IL(ACUR, BCUR, ANXT, BNXT, rdslot, stslot, stku) do {             \
    STAGE(stslot, stku);                                                       \
    SP(1);                                                                     \
    _Pragma("unroll") for (int s_ = 0; s_ < 8; ++s_) {                         \
      _Pragma("unroll") for (int j_ = 0; j_ < 4; ++j_)                         \
        acc[s_][j_] = __builtin_amdgcn_mfma_f32_16x16x32_bf16(                 \
            ACUR[s_], BCUR[j_], acc[s_][j_], 0, 0, 0);                         \
      ANXT[s_] = *(const bf16x8*)(&As[rdslot][areadbase + s_*512]);            \
      if (s_ < 4)                                                              \
        BNXT[s_] = *(const bf16x8*)(&Bs[rdslot][breadbase + s_*512]);          \
    }                                                                          \
    SP(0);                                                                     \
    VMC(4); SB0(); BAR(); } while(0)
#define BAR() __builtin_amdgcn_s_barrier()
#define VMC(n) asm volatile("s_waitcnt vmcnt(" #n ")" ::: "memory")
#define SB0() __builtin_amdgcn_sched_barrier(0)
#define SP(n) __builtin_amdgcn_s_setprio(n)

__global__ __launch_bounds__(512, 1) void caps_conv2(
    const unsigned short* __restrict__ Aap,  // Apad NHWC bf16
    const unsigned short* __restrict__ BT,   // [256][6400] bf16
    unsigned short* __restrict__ Pp)         // 2 x [32768][256] bf16 partials
{
  __shared__ __attribute__((aligned(16))) unsigned short As[4][8192];
  __shared__ __attribute__((aligned(16))) unsigned short Bs[4][8192];

  const int tid = threadIdx.x;
  const int bid = blockIdx.x;          // 256 blocks
  const int lid = (bid & 7) * 32 + (bid >> 3);   // bijective XCD-chunked swizzle
  const int kid = lid & 1;
  const int m0 = (lid >> 1) << 8;
  const int t0 = kid * 100;            // 100 k-units of 32 per split-K half
  const int wid = tid >> 6;
  const int l = tid & 63;

  const int swz = (l & 3) ^ ((l >> 3) & 3);   // matches read part q^((row>>1)&3)
  int abase0, abase1, bbase0, bbase1;
  {
    int ra = wid * 16 + (l >> 2);               // 0..127
    int m = m0 + ra;
    int b = m >> 14, hw = m & 16383, h = hw >> 7, w = hw & 127;
    abase0 = ((b * 132 + h) * 132 + w) * 256 + swz * 8;
    m = m0 + ra + 128;
    b = m >> 14; hw = m & 16383; h = hw >> 7; w = hw & 127;
    abase1 = ((b * 132 + h) * 132 + w) * 256 + swz * 8;
    bbase0 = ra * 6400 + swz * 8;
    bbase1 = (ra + 128) * 6400 + swz * 8;
  }
  const int sA = wid * 512;            // LDS stage base (ushorts)

  const int rl = l & 15, q = l >> 4;
  const int wm = wid >> 2, wn = wid & 3;       // 2x4 wave grid, tile 128x64
  const int areadbase = (wm * 128 + rl) * 32 + ((q ^ ((rl >> 1) & 3)) << 3);
  const int breadbase = (wn * 64 + rl) * 32 + ((q ^ ((rl >> 1) & 3)) << 3);

  f32x4 acc[8][4] = {};
  bf16x8 aR0[8], bR0[4], aR1[8], bR1[4];

  STAGE(0, t0 + 0); STAGE(1, t0 + 1); STAGE(2, t0 + 2);
  VMC(4); BAR();
  READ_SET(aR0, bR0, 0);

  // main loop: bodies 0..95 (48 iters x 2), interleaved reads
  for (int it = 0; it < 48; ++it) {
    const int u = it * 2;
    BODY_IL(aR0, bR0, aR1, bR1, (u + 1) & 3, (u + 3) & 3, t0 + u + 3);
    BODY_IL(aR1, bR1, aR0, bR0, (u + 2) & 3, (u + 4) & 3, t0 + u + 4);
  }
  // peeled tail (r8-exact): state on entry = aR0/bR0 hold unit 96,
  // staged through unit 98 (slot 2)
  READ_SET(aR1, bR1, 1);
  STAGE(3, t0 + 99);
  SP(1); MFMA_SET(aR0, bR0); SP(0);
  VMC(4); SB0(); BAR();
  READ_SET(aR0, bR0, 2);
  SP(1); MFMA_SET(aR1, bR1); SP(0);
  VMC(0); SB0(); BAR();
  READ_SET(aR1, bR1, 3);
  SP(1); MFMA_SET(aR0, bR0); SP(0);
  MFMA_SET(aR1, bR1);

  unsigned short* P = Pp + kid * 8388608;
#pragma unroll
  for (int s = 0; s < 8; ++s) {
#pragma unroll
    for (int j = 0; j < 4; ++j) {
      int col = wn * 64 + j * 16 + rl;
      int mrow = m0 + wm * 128 + s * 16 + (q << 2);
#pragma unroll
      for (int e = 0; e < 4; ++e)
        P[(size_t)(mrow + e) * 256 + col] = f2bf(acc[s][j][e]);
    }
  }
}

// --- K3: tail, scalarized weights (r11 config) ------------------------------
__global__ __launch_bounds__(128) void tail_k4(
    const unsigned short* __restrict__ Pp, const float* __restrict__ y,
    const float* __restrict__ bp, const float* __restrict__ cbp,
    const float* __restrict__ Ws, const float* __restrict__ bs,
    const float* __restrict__ cbs,
    const float* __restrict__ Wr1, const float* __restrict__ br1,
    const float* __restrict__ Wr2, const float* __restrict__ br2,
    const float* __restrict__ Wr3, const float* __restrict__ br3,
    float* __restrict__ out) {
  __shared__ float pp[2][64][8];
  __shared__ float r1l[64][65];
  __shared__ float snk[2][64];

  const int tid = threadIdx.x;
  const int w = __builtin_amdgcn_readfirstlane(tid >> 6);
  const int l = tid & 63;
  const int m = blockIdx.x * 64 + l;

  const us8* pr0 = (const us8*)(Pp + (size_t)m * 256) + w * 16;
  const us8* pr1 = (const us8*)(Pp + 8388608 + (size_t)m * 256) + w * 16;
  float P8[8] = {0.f, 0.f, 0.f, 0.f, 0.f, 0.f, 0.f, 0.f};
#pragma unroll 4
  for (int i = 0; i < 16; ++i) {
    const int ci = (w * 16 + i) * 8;
    us8 a = pr0[i], b = pr1[i];
    float v[8];
#pragma unroll
    for (int c = 0; c < 8; ++c)
      v[c] = (bf2f(a[c]) + bf2f(b[c])) * (1.f / 32.f)
           + (bp[ci + c] * (1.f / 32.f) + cbp[ci + c]);
    float sqa = v[0]*v[0] + v[1]*v[1] + v[2]*v[2] + v[3]*v[3];
    float sqb = v[4]*v[4] + v[5]*v[5] + v[6]*v[6] + v[7]*v[7];
    float sq = sqa + sqb;
    float scale = sq / ((1.f + sq) * sqrtf(sq + 1e-9f));
#pragma unroll
    for (int c = 0; c < 8; ++c) P8[c] += v[c] * scale;
  }
#pragma unroll
  for (int c = 0; c < 8; ++c) pp[w][l][c] = P8[c];
  __syncthreads();
#pragma unroll
  for (int c = 0; c < 8; ++c) P8[c] = pp[0][l][c] + pp[1][l][c];

  float pre[16];
  float sqx = 0.f, sqy = 0.f;
#pragma unroll
  for (int a = 0; a < 16; ++a) {
    float s0 = P8[0]*Ws[a*8+0] + P8[1]*Ws[a*8+1] + P8[2]*Ws[a*8+2] + P8[3]*Ws[a*8+3];
    float s1 = P8[4]*Ws[a*8+4] + P8[5]*Ws[a*8+5] + P8[6]*Ws[a*8+6] + P8[7]*Ws[a*8+7];
    float s = (32.f * bs[a] + cbs[a]) + s0 + s1;
    pre[a] = s;
    if (a & 1) sqy += s * s; else sqx += s * s;
  }
  float sq2 = sqx + sqy;
  float sc2 = sq2 / ((1.f + sq2) * sqrtf(sq2 + 1e-9f));
  if (w == 0) out[m] = sqrtf(sq2 * sc2 * sc2 + 1e-9f);

  const float f = sc2 * y[m];
  float pf[16];
#pragma unroll
  for (int a = 0; a < 16; ++a) pf[a] = pre[a] * f;

#pragma unroll
  for (int jj = 0; jj < 32; ++jj) {
    const int j = w * 32 + jj;
    float s0 = 0.f, s1 = 0.f;
#pragma unroll
    for (int a = 0; a < 8; ++a) {
      s0 += pf[a] * Wr1[j * 16 + a];
      s1 += pf[a + 8] * Wr1[j * 16 + a + 8];
    }
    r1l[l][j] = fmaxf(br1[j] + s0 + s1, 0.f);
  }
  __syncthreads();
  float r1f[64];
#pragma unroll
  for (int j = 0; j < 64; ++j) r1f[j] = r1l[l][j];

  float a0 = 0.f, a1 = 0.f, a2 = 0.f, a3 = 0.f;
#pragma unroll 4
  for (int kk = 0; kk < 64; ++kk) {
    const int k = w * 64 + kk;
    const float* wr = Wr2 + k * 64;
    float s0 = 0.f, s1 = 0.f, s2 = 0.f, s3 = 0.f;
#pragma unroll
    for (int j = 0; j < 16; ++j) {
      s0 += r1f[j] * wr[j];           s1 += r1f[j + 16] * wr[j + 16];
      s2 += r1f[j + 32] * wr[j + 32]; s3 += r1f[j + 48] * wr[j + 48];
    }
    float s = br2[k] + (s0 + s1) + (s2 + s3);
    float t = fmaxf(s, 0.f) * Wr3[k];
    switch (kk & 3) { case 0: a0 += t; break; case 1: a1 += t; break;
                      case 2: a2 += t; break; default: a3 += t; }
  }
  float own = (a0 + a1) + (a2 + a3);
  snk[w][l] = own;
  __syncthreads();
  if (w == 0) {
    float acc2 = br3[0] + own + snk[1][l];
    out[32768 + m] = 1.f / (1.f + expf(-acc2));
  }
}

// ---------------------------------------------------------------------------
extern "C" void kernel_launch(void* const* d_in, const int* in_sizes, int n_in,
                              void* d_out, int out_size, void* d_ws, size_t ws_size,
                              hipStream_t stream) {
  const float* x   = (const float*)d_in[0];
  const float* y   = (const float*)d_in[1];
  const float* W1  = (const float*)d_in[2];
  const float* b1  = (const float*)d_in[3];
  const float* Wp  = (const float*)d_in[4];
  const float* bp  = (const float*)d_in[5];
  const float* cbp = (const float*)d_in[6];
  const float* Ws  = (const float*)d_in[7];
  const float* bs  = (const float*)d_in[8];
  const float* cbs = (const float*)d_in[9];
  const float* Wr1 = (const float*)d_in[10];
  const float* br1 = (const float*)d_in[11];
  const float* Wr2 = (const float*)d_in[12];
  const float* br2 = (const float*)d_in[13];
  const float* Wr3 = (const float*)d_in[14];
  const float* br3 = (const float*)d_in[15];
  float* out = (float*)d_out;

  char* ws = (char*)d_ws;
  unsigned short* Apad = (unsigned short*)ws;
  unsigned short* BT   = (unsigned short*)(ws + BT_OFF);
  unsigned short* Pp   = (unsigned short*)(ws + PP_OFF);

  hipLaunchKernelGGL(pre_k, dim3(4612), dim3(256), 0, stream, x, W1, b1, Wp, BT, Apad);
  hipLaunchKernelGGL(caps_conv2, dim3(256), dim3(512), 0, stream, Apad, BT, Pp);
  hipLaunchKernelGGL(tail_k4, dim3(512), dim3(128), 0, stream,
                     Pp, y, bp, cbp, Ws, bs, cbs, Wr1, br1, Wr2, br2, Wr3, br3, out);
}

// Round 17
// 143.767 us; speedup vs baseline: 1.0326x; 1.0326x over previous
//
#include <hip/hip_runtime.h>
#include <hip/hip_bf16.h>

typedef __attribute__((ext_vector_type(8))) unsigned short us8;
typedef __attribute__((ext_vector_type(8))) __bf16 bf16x8;
typedef __attribute__((ext_vector_type(4))) float f32x4;

__device__ __forceinline__ unsigned short f2bf(float f) {
  unsigned int u = __float_as_uint(f);
  u += 0x7FFFu + ((u >> 16) & 1u);   // round-to-nearest-even
  return (unsigned short)(u >> 16);
}
__device__ __forceinline__ float bf2f(unsigned short u) {
  return __uint_as_float(((unsigned int)u) << 16);
}

// direct global->LDS DMA, 16B per lane (dest = wave-uniform base + lane*16)
__device__ __forceinline__ void gld16(const unsigned short* g, unsigned short* l) {
  __builtin_amdgcn_global_load_lds(reinterpret_cast<const unsigned int*>(g),
                                   reinterpret_cast<unsigned int*>(l), 16, 0, 0);
}

// ---------------------------------------------------------------------------
// ws layout (bytes)
//   Apad : [2][132][132][256] bf16 = 17,842,176
//   BT   : [256][6400] bf16 (k=(dh*5+dw)*256+c)
//   Pp   : 2 x [32768][256] bf16 partials = 33,554,432
// total = 54,673,408
// ---------------------------------------------------------------------------
#define BT_OFF     17842176
#define PP_OFF     21118976

// --- K1: fused conv1 (blocks 0..4095) + weight prep (4096..4351) +
//         halo zero (4352..4611) --------------------------------------------
__global__ __launch_bounds__(256) void pre_k(const float* __restrict__ x,
                                             const float* __restrict__ W1,
                                             const float* __restrict__ b1,
                                             const float* __restrict__ Wp,
                                             unsigned short* __restrict__ BT,
                                             unsigned short* __restrict__ Apad) {
  __shared__ float w[6400];
  const int bid = blockIdx.x, t = threadIdx.x;
  if (bid < 4096) {
    int pxt = bid >> 3;
    int cq  = bid & 7;
    int px  = (pxt << 6) + (t & 63);
    int cg  = __builtin_amdgcn_readfirstlane(t >> 6);
    int co0 = (cq << 5) + (cg << 3);
    int b = px >> 14, hw = px & 16383;
    int h = hw >> 7, wcol = hw & 127;

    float patch[25];
#pragma unroll
    for (int dh = 0; dh < 5; ++dh)
#pragma unroll
      for (int dw = 0; dw < 5; ++dw) {
        int hh = h + dh - 2, ww = wcol + dw - 2;
        bool ok = (hh >= 0) & (hh < 128) & (ww >= 0) & (ww < 128);
        patch[dh * 5 + dw] = ok ? x[(b << 14) + hh * 128 + ww] : 0.f;
      }
    us8 o;
#pragma unroll
    for (int c = 0; c < 8; ++c) {
      float acc = b1[co0 + c];
#pragma unroll
      for (int i = 0; i < 25; ++i) acc += patch[i] * W1[(co0 + c) * 25 + i];
      o[c] = f2bf(fmaxf(acc, 0.f));
    }
    *(us8*)(Apad + (size_t)((b * 132 + h + 2) * 132 + (wcol + 2)) * 256 + co0) = o;
  } else if (bid < 4352) {
    const int n = bid - 4096;
    const float* src = Wp + n * 6400;
    for (int i = t; i < 6400; i += 256) w[i] = src[i];
    __syncthreads();
    for (int k = t; k < 6400; k += 256) {
      int dhw = k >> 8, c = k & 255;
      BT[n * 6400 + k] = f2bf(w[c * 25 + dhw]);
    }
  } else {
    int idx = (bid - 4352) * 256 + t;
    int chunk = idx & 31;
    int pix = idx >> 5;
    int img = pix >= 1040;
    int p = pix - img * 1040;
    int h, w2;
    if (p < 528) {
      int rs = p / 132;
      h = (rs < 2) ? rs : rs + 128;
      w2 = p - rs * 132;
    } else {
      int q = p - 528;
      h = 2 + (q >> 2);
      int cs = q & 3;
      w2 = (cs < 2) ? cs : cs + 128;
    }
    us8 z = {0, 0, 0, 0, 0, 0, 0, 0};
    *(us8*)(Apad + (size_t)(img * 17424 + h * 132 + w2) * 256 + chunk * 8) = z;
  }
}

// --- K2: implicit-GEMM conv (EXACT r8/r11/r15 config: ~96us, MfmaUtil 47) --
// 256x256 tile, 8 waves, split-K=2, 4-slot BK=32 ring (A+B in LDS, 128 KB),
// reg-double-buffered frags, ONE barrier + ONE counted VMC(4) per k-unit.
#define STAGE(slot, ku) do { int dhw_=(ku)>>3, dh_=dhw_/5, dw_=dhw_-dh_*5;     \
    int ao_=((dh_*132+dw_)<<8)+(((ku)&7)<<5);                                  \
    int kp_=(ku)<<5;                                                           \
    gld16(Aap+abase0+ao_, &As[slot][sA]);                                      \
    gld16(Aap+abase1+ao_, &As[slot][sA+4096]);                                 \
    gld16(BT+bbase0+kp_, &Bs[slot][sA]);                                       \
    gld16(BT+bbase1+kp_, &Bs[slot][sA+4096]); } while(0)
#define READ_SET(AST, BST, slot) do {                                          \
  _Pragma("unroll") for (int s_ = 0; s_ < 8; ++s_)                             \
    AST[s_] = *(const bf16x8*)(&As[slot][areadbase + s_*512]);                 \
  _Pragma("unroll") for (int j_ = 0; j_ < 4; ++j_)                             \
    BST[j_] = *(const bf16x8*)(&Bs[slot][breadbase + j_*512]); } while(0)
#define MFMA_SET(AST, BST) do {                                                \
  _Pragma("unroll") for (int s_ = 0; s_ < 8; ++s_)                             \
  _Pragma("unroll") for (int j_ = 0; j_ < 4; ++j_)                             \
    acc[s_][j_] = __builtin_amdgcn_mfma_f32_16x16x32_bf16(                     \
        AST[s_], BST[j_], acc[s_][j_], 0, 0, 0); } while(0)
#define BAR() __builtin_amdgcn_s_barrier()
#define VMC(n) asm volatile("s_waitcnt vmcnt(" #n ")" ::: "memory")
#define SB0() __builtin_amdgcn_sched_barrier(0)
#define SP(n) __builtin_amdgcn_s_setprio(n)

__global__ __launch_bounds__(512, 1) void caps_conv2(
    const unsigned short* __restrict__ Aap,  // Apad NHWC bf16
    const unsigned short* __restrict__ BT,   // [256][6400] bf16
    unsigned short* __restrict__ Pp)         // 2 x [32768][256] bf16 partials
{
  __shared__ __attribute__((aligned(16))) unsigned short As[4][8192];
  __shared__ __attribute__((aligned(16))) unsigned short Bs[4][8192];

  const int tid = threadIdx.x;
  const int bid = blockIdx.x;          // 256 blocks
  const int lid = (bid & 7) * 32 + (bid >> 3);   // bijective XCD-chunked swizzle
  const int kid = lid & 1;
  const int m0 = (lid >> 1) << 8;
  const int t0 = kid * 100;            // 100 k-units of 32 per split-K half
  const int wid = tid >> 6;
  const int l = tid & 63;

  const int swz = (l & 3) ^ ((l >> 3) & 3);   // matches read part q^((row>>1)&3)
  int abase0, abase1, bbase0, bbase1;
  {
    int ra = wid * 16 + (l >> 2);               // 0..127
    int m = m0 + ra;
    int b = m >> 14, hw = m & 16383, h = hw >> 7, w = hw & 127;
    abase0 = ((b * 132 + h) * 132 + w) * 256 + swz * 8;
    m = m0 + ra + 128;
    b = m >> 14; hw = m & 16383; h = hw >> 7; w = hw & 127;
    abase1 = ((b * 132 + h) * 132 + w) * 256 + swz * 8;
    bbase0 = ra * 6400 + swz * 8;
    bbase1 = (ra + 128) * 6400 + swz * 8;
  }
  const int sA = wid * 512;            // LDS stage base (ushorts)

  const int rl = l & 15, q = l >> 4;
  const int wm = wid >> 2, wn = wid & 3;       // 2x4 wave grid, tile 128x64
  const int areadbase = (wm * 128 + rl) * 32 + ((q ^ ((rl >> 1) & 3)) << 3);
  const int breadbase = (wn * 64 + rl) * 32 + ((q ^ ((rl >> 1) & 3)) << 3);

  f32x4 acc[8][4] = {};
  bf16x8 aR0[8], bR0[4], aR1[8], bR1[4];

  STAGE(0, t0 + 0); STAGE(1, t0 + 1); STAGE(2, t0 + 2);
  VMC(4); BAR();
  READ_SET(aR0, bR0, 0);

  for (int it = 0; it < 48; ++it) {
    const int u = it * 2;
    READ_SET(aR1, bR1, (u + 1) & 3);
    STAGE((u + 3) & 3, t0 + u + 3);
    SP(1); MFMA_SET(aR0, bR0); SP(0);
    VMC(4); SB0(); BAR();
    READ_SET(aR0, bR0, (u + 2) & 3);
    STAGE((u + 4) & 3, t0 + u + 4);
    SP(1); MFMA_SET(aR1, bR1); SP(0);
    VMC(4); SB0(); BAR();
  }
  READ_SET(aR1, bR1, 1);
  STAGE(3, t0 + 99);
  SP(1); MFMA_SET(aR0, bR0); SP(0);
  VMC(4); SB0(); BAR();
  READ_SET(aR0, bR0, 2);
  SP(1); MFMA_SET(aR1, bR1); SP(0);
  VMC(0); SB0(); BAR();
  READ_SET(aR1, bR1, 3);
  SP(1); MFMA_SET(aR0, bR0); SP(0);
  MFMA_SET(aR1, bR1);

  unsigned short* P = Pp + kid * 8388608;
#pragma unroll
  for (int s = 0; s < 8; ++s) {
#pragma unroll
    for (int j = 0; j < 4; ++j) {
      int col = wn * 64 + j * 16 + rl;
      int mrow = m0 + wm * 128 + s * 16 + (q << 2);
#pragma unroll
      for (int e = 0; e < 4; ++e)
        P[(size_t)(mrow + e) * 256 + col] = f2bf(acc[s][j][e]);
    }
  }
}

// --- K3: tail, scalarized weights (r11 config) ------------------------------
__global__ __launch_bounds__(128) void tail_k4(
    const unsigned short* __restrict__ Pp, const float* __restrict__ y,
    const float* __restrict__ bp, const float* __restrict__ cbp,
    const float* __restrict__ Ws, const float* __restrict__ bs,
    const float* __restrict__ cbs,
    const float* __restrict__ Wr1, const float* __restrict__ br1,
    const float* __restrict__ Wr2, const float* __restrict__ br2,
    const float* __restrict__ Wr3, const float* __restrict__ br3,
    float* __restrict__ out) {
  __shared__ float pp[2][64][8];
  __shared__ float r1l[64][65];
  __shared__ float snk[2][64];

  const int tid = threadIdx.x;
  const int w = __builtin_amdgcn_readfirstlane(tid >> 6);
  const int l = tid & 63;
  const int m = blockIdx.x * 64 + l;

  const us8* pr0 = (const us8*)(Pp + (size_t)m * 256) + w * 16;
  const us8* pr1 = (const us8*)(Pp + 8388608 + (size_t)m * 256) + w * 16;
  float P8[8] = {0.f, 0.f, 0.f, 0.f, 0.f, 0.f, 0.f, 0.f};
#pragma unroll 4
  for (int i = 0; i < 16; ++i) {
    const int ci = (w * 16 + i) * 8;
    us8 a = pr0[i], b = pr1[i];
    float v[8];
#pragma unroll
    for (int c = 0; c < 8; ++c)
      v[c] = (bf2f(a[c]) + bf2f(b[c])) * (1.f / 32.f)
           + (bp[ci + c] * (1.f / 32.f) + cbp[ci + c]);
    float sqa = v[0]*v[0] + v[1]*v[1] + v[2]*v[2] + v[3]*v[3];
    float sqb = v[4]*v[4] + v[5]*v[5] + v[6]*v[6] + v[7]*v[7];
    float sq = sqa + sqb;
    float scale = sq / ((1.f + sq) * sqrtf(sq + 1e-9f));
#pragma unroll
    for (int c = 0; c < 8; ++c) P8[c] += v[c] * scale;
  }
#pragma unroll
  for (int c = 0; c < 8; ++c) pp[w][l][c] = P8[c];
  __syncthreads();
#pragma unroll
  for (int c = 0; c < 8; ++c) P8[c] = pp[0][l][c] + pp[1][l][c];

  float pre[16];
  float sqx = 0.f, sqy = 0.f;
#pragma unroll
  for (int a = 0; a < 16; ++a) {
    float s0 = P8[0]*Ws[a*8+0] + P8[1]*Ws[a*8+1] + P8[2]*Ws[a*8+2] + P8[3]*Ws[a*8+3];
    float s1 = P8[4]*Ws[a*8+4] + P8[5]*Ws[a*8+5] + P8[6]*Ws[a*8+6] + P8[7]*Ws[a*8+7];
    float s = (32.f * bs[a] + cbs[a]) + s0 + s1;
    pre[a] = s;
    if (a & 1) sqy += s * s; else sqx += s * s;
  }
  float sq2 = sqx + sqy;
  float sc2 = sq2 / ((1.f + sq2) * sqrtf(sq2 + 1e-9f));
  if (w == 0) out[m] = sqrtf(sq2 * sc2 * sc2 + 1e-9f);

  const float f = sc2 * y[m];
  float pf[16];
#pragma unroll
  for (int a = 0; a < 16; ++a) pf[a] = pre[a] * f;

#pragma unroll
  for (int jj = 0; jj < 32; ++jj) {
    const int j = w * 32 + jj;
    float s0 = 0.f, s1 = 0.f;
#pragma unroll
    for (int a = 0; a < 8; ++a) {
      s0 += pf[a] * Wr1[j * 16 + a];
      s1 += pf[a + 8] * Wr1[j * 16 + a + 8];
    }
    r1l[l][j] = fmaxf(br1[j] + s0 + s1, 0.f);
  }
  __syncthreads();
  float r1f[64];
#pragma unroll
  for (int j = 0; j < 64; ++j) r1f[j] = r1l[l][j];

  float a0 = 0.f, a1 = 0.f, a2 = 0.f, a3 = 0.f;
#pragma unroll 4
  for (int kk = 0; kk < 64; ++kk) {
    const int k = w * 64 + kk;
    const float* wr = Wr2 + k * 64;
    float s0 = 0.f, s1 = 0.f, s2 = 0.f, s3 = 0.f;
#pragma unroll
    for (int j = 0; j < 16; ++j) {
      s0 += r1f[j] * wr[j];           s1 += r1f[j + 16] * wr[j + 16];
      s2 += r1f[j + 32] * wr[j + 32]; s3 += r1f[j + 48] * wr[j + 48];
    }
    float s = br2[k] + (s0 + s1) + (s2 + s3);
    float t = fmaxf(s, 0.f) * Wr3[k];
    switch (kk & 3) { case 0: a0 += t; break; case 1: a1 += t; break;
                      case 2: a2 += t; break; default: a3 += t; }
  }
  float own = (a0 + a1) + (a2 + a3);
  snk[w][l] = own;
  __syncthreads();
  if (w == 0) {
    float acc2 = br3[0] + own + snk[1][l];
    out[32768 + m] = 1.f / (1.f + expf(-acc2));
  }
}

// ---------------------------------------------------------------------------
extern "C" void kernel_launch(void* const* d_in, const int* in_sizes, int n_in,
                              void* d_out, int out_size, void* d_ws, size_t ws_size,
                              hipStream_t stream) {
  const float* x   = (const float*)d_in[0];
  const float* y   = (const float*)d_in[1];
  const float* W1  = (const float*)d_in[2];
  const float* b1  = (const float*)d_in[3];
  const float* Wp  = (const float*)d_in[4];
  const float* bp  = (const float*)d_in[5];
  const float* cbp = (const float*)d_in[6];
  const float* Ws  = (const float*)d_in[7];
  const float* bs  = (const float*)d_in[8];
  const float* cbs = (const float*)d_in[9];
  const float* Wr1 = (const float*)d_in[10];
  const float* br1 = (const float*)d_in[11];
  const float* Wr2 = (const float*)d_in[12];
  const float* br2 = (const float*)d_in[13];
  const float* Wr3 = (const float*)d_in[14];
  const float* br3 = (const float*)d_in[15];
  float* out = (float*)d_out;

  char* ws = (char*)d_ws;
  unsigned short* Apad = (unsigned short*)ws;
  unsigned short* BT   = (unsigned short*)(ws + BT_OFF);
  unsigned short* Pp   = (unsigned short*)(ws + PP_OFF);

  hipLaunchKernelGGL(pre_k, dim3(4612), dim3(256), 0, stream, x, W1, b1, Wp, BT, Apad);
  hipLaunchKernelGGL(caps_conv2, dim3(256), dim3(512), 0, stream, Apad, BT, Pp);
  hipLaunchKernelGGL(tail_k4, dim3(512), dim3(128), 0, stream,
                     Pp, y, bp, cbp, Ws, bs, cbs, Wr1, br1, Wr2, br2, Wr3, br3, out);
}